// Round 1
// 747.200 us; speedup vs baseline: 1.1163x; 1.1163x over previous
//
#include <hip/hip_runtime.h>
#include <hip/hip_bf16.h>

// Binary conv: out = conv2d(x, sign(w)), SAME, stride 1, NHWC.
// x: (32,112,112,128) f32, w: (3,3,128,256) f32, out: (32,112,112,256) f32.
//
// Round 3: B (weights, 576 KB, L2-resident) moved out of LDS into per-wave
// registers, loaded coalesced from a fragment-ordered pack. Removes all
// main-loop barriers + halves LDS traffic. A tile XOR-swizzled (no pad),
// LDS 46 KB -> 3 blocks/CU (12 waves/CU).

#define TH 8
#define TW 16
#define PH 10          // TH + 2 halo
#define PW 18          // TW + 2 halo
#define APIX (PH * PW) // 180 pixels

typedef __attribute__((ext_vector_type(8))) short bf16x8;
typedef __attribute__((ext_vector_type(4))) float f32x4;

static __device__ inline ushort f2bf_rne(float f) {
    union { float f; unsigned u; } c; c.f = f;
    unsigned u = c.u;
    unsigned r = (u + 0x7FFFu + ((u >> 16) & 1u)) >> 16;
    return (ushort)r;
}

// ---- Prep: pack sign(w) -> bf16 in per-lane fragment order:
//      wp[t][c][p][ng][lane][j]  (t: oc half, c: 18 K-chunks of 64,
//      p: K sub-half of 32, ng: oc group of 16, lane=quad*16+l15, j: 0..7)
//      element: oc = t*128 + ng*16 + l15,
//               k-within-chunk = p*32 + quad*8 + j
//      chunk c -> kh=c/6, kw=(c%6)>>1, h=c&1; ic = h*64 + p*32 + quad*8 + j.
__global__ void pack_w_kernel(const float* __restrict__ w, ushort* __restrict__ wp) {
    int u = blockIdx.x * 256 + threadIdx.x;   // 0 .. 36863
    int lane = u & 63;
    int l15  = lane & 15;
    int quad = lane >> 4;
    int v  = u >> 6;
    int ng = v & 7;
    int p  = (v >> 3) & 1;
    int cc = v >> 4;           // t*18 + c
    int c  = cc % 18;
    int t  = cc / 18;
    int kh = c / 6;
    int r6 = c % 6;
    int kw = r6 >> 1;
    int h  = r6 & 1;
    int oc  = t * 128 + ng * 16 + l15;
    int icb = h * 64 + (p * 4 + quad) * 8;
    const float* src = w + (size_t)((kh * 3 + kw) * 128 + icb) * 256 + oc;
    ushort b[8];
    #pragma unroll
    for (int j = 0; j < 8; ++j) {
        float vv = src[(size_t)j * 256];
        b[j] = (vv > 0.f) ? (ushort)0x3F80u : ((vv < 0.f) ? (ushort)0xBF80u : (ushort)0u);
    }
    uint4 pv;
    pv.x = (unsigned)b[0] | ((unsigned)b[1] << 16);
    pv.y = (unsigned)b[2] | ((unsigned)b[3] << 16);
    pv.z = (unsigned)b[4] | ((unsigned)b[5] << 16);
    pv.w = (unsigned)b[6] | ((unsigned)b[7] << 16);
    // dest: (((cc*2 + p)*8 + ng)*64 + lane) * 8 ushorts
    *(uint4*)(wp + ((((size_t)cc * 2 + p) * 8 + ng) * 64 + lane) * 8) = pv;
}

__global__ __launch_bounds__(256, 3)
void binary_conv_kernel(const float* __restrict__ x, const ushort* __restrict__ wp,
                        float* __restrict__ out)
{
    // A tile: [pix][128 ic] bf16, 16B ic-chunk index XOR-swizzled by (pix&7).
    // 46080 B -> 3 blocks/CU.
    __shared__ __align__(16) ushort At[APIX * 128];

    const int tid = threadIdx.x;
    const int bx  = blockIdx.x;
    const int oc0 = blockIdx.y << 7;
    const int wt   = bx % 7;
    const int ht   = (bx / 7) % 14;
    const int nimg = bx / 98;
    const int h0 = ht * TH;
    const int w0 = wt * TW;

    const int wave = tid >> 6;
    const int lane = tid & 63;
    const int l15  = lane & 15;
    const int quad = lane >> 4;
    const int wm   = wave >> 1;
    const int wn   = wave & 1;

    // Per-lane B fragment source base (fragment-ordered pack, coalesced 1KB/wave)
    const ushort* wsrc = wp + (size_t)blockIdx.y * 147456
                            + (size_t)(wn * 4) * 512 + (size_t)lane * 8;

    bf16x8 ba[8], bb[8];
    auto loadB = [&](bf16x8 (&b)[8], int c) {
        const ushort* s = wsrc + (size_t)c * 8192;   // c*16*512
        #pragma unroll
        for (int p = 0; p < 2; ++p)
            #pragma unroll
            for (int nt = 0; nt < 4; ++nt)
                b[p * 4 + nt] = *(const bf16x8*)(s + (p * 8 + nt) * 512);
    };

    // Prefetch chunk 0's B fragments before/under A staging
    loadB(ba, 0);

    // ---- Stage A once: 10x18 pixel tile with halo, 128 ic, fp32 -> bf16 ----
    const float* xbase = x + (size_t)nimg * (112 * 112 * 128);
    for (int g = tid; g < APIX * 32; g += 256) {
        int pix = g >> 5;
        int ic  = (g & 31) << 2;
        int ph  = pix / PW;
        int pw  = pix - ph * PW;
        int hh  = h0 + ph - 1;
        int ww  = w0 + pw - 1;
        uint2 val; val.x = 0u; val.y = 0u;
        if ((unsigned)hh < 112u && (unsigned)ww < 112u) {
            const float4 v = *(const float4*)(xbase + ((size_t)(hh * 112 + ww) * 128 + ic));
            val.x = (unsigned)f2bf_rne(v.x) | ((unsigned)f2bf_rne(v.y) << 16);
            val.y = (unsigned)f2bf_rne(v.z) | ((unsigned)f2bf_rne(v.w) << 16);
        }
        int sw = (((ic >> 3) ^ (pix & 7)) << 3) + (ic & 7);
        *(uint2*)&At[pix * 128 + sw] = val;
    }

    f32x4 acc[4][4];
    #pragma unroll
    for (int mt = 0; mt < 4; ++mt)
        #pragma unroll
        for (int nt = 0; nt < 4; ++nt)
            acc[mt][nt] = (f32x4){0.f, 0.f, 0.f, 0.f};

    __syncthreads();   // A tile ready; ONLY barrier in the kernel

    auto compute = [&](int c, bf16x8 (&b)[8]) {
        const int kh  = c / 6;
        const int r6  = c % 6;
        const int kwv = r6 >> 1;
        const int hlf = r6 & 1;
        const int col = l15 + kwv;
        #pragma unroll
        for (int p = 0; p < 2; ++p) {
            const int ch = hlf * 8 + p * 4 + quad;   // 16B ic-chunk index
            bf16x8 af[4];
            #pragma unroll
            for (int mt = 0; mt < 4; ++mt) {
                int pix = (wm * 4 + mt + kh) * PW + col;
                af[mt] = *(const bf16x8*)&At[pix * 128 + ((ch ^ (pix & 7)) << 3)];
            }
            #pragma unroll
            for (int mt = 0; mt < 4; ++mt)
                #pragma unroll
                for (int nt = 0; nt < 4; ++nt)
                    acc[mt][nt] = __builtin_amdgcn_mfma_f32_16x16x32_bf16(
                        af[mt], b[p * 4 + nt], acc[mt][nt], 0, 0, 0);
        }
    };

    // Main loop: no barriers; B double-buffered in registers, prefetch 1 chunk ahead.
    for (int cc = 0; cc < 18; cc += 2) {
        loadB(bb, cc + 1);
        compute(cc, ba);
        if (cc + 2 < 18) loadB(ba, cc + 2);
        compute(cc + 1, bb);
    }

    // ---- Epilogue: C/D layout col=lane&15, row=quad*4+reg ----
    float* obase = out + ((size_t)nimg * 112 * 112) * 256 + oc0 + wn * 64 + l15;
    #pragma unroll
    for (int mt = 0; mt < 4; ++mt) {
        #pragma unroll
        for (int r = 0; r < 4; ++r) {
            int m  = wm * 64 + mt * 16 + quad * 4 + r;
            int dh = m >> 4;
            int dw = m & 15;
            float* orow = obase + (size_t)((h0 + dh) * 112 + (w0 + dw)) * 256;
            #pragma unroll
            for (int nt = 0; nt < 4; ++nt)
                orow[nt * 16] = acc[mt][nt][r];
        }
    }
}

extern "C" void kernel_launch(void* const* d_in, const int* in_sizes, int n_in,
                              void* d_out, int out_size, void* d_ws, size_t ws_size,
                              hipStream_t stream) {
    const float* x = (const float*)d_in[0];
    const float* w = (const float*)d_in[1];
    float* out = (float*)d_out;
    ushort* wpack = (ushort*)d_ws;   // 589824 B

    hipLaunchKernelGGL(pack_w_kernel, dim3(144), dim3(256), 0, stream, w, wpack);

    dim3 grid(32 * 14 * 7, 2);
    hipLaunchKernelGGL(binary_conv_kernel, grid, dim3(256), 0, stream, x, wpack, out);
}